// Round 2
// baseline (166.826 us; speedup 1.0000x reference)
//
#include <hip/hip_runtime.h>

#define HID   128
#define PNUM  1024
#define NB    64
#define LASTB 63
#define BP    (NB * PNUM)   // 65536 points
#define HBLK  128           // harmonic-count blocks
#define MBLK  (BP / 256)    // 256 MLP blocks (1 point/thread)
#define NBLK  (HBLK + MBLK)

__device__ __forceinline__ unsigned long long umax64(unsigned long long a,
                                                     unsigned long long b) {
    return a > b ? a : b;
}

// ---------------------------------------------------------------------------
// Single fused kernel.
//   blocks [HBLK, NBLK): MLP, 1 point/thread, h1[128] in VGPRs, W2 via
//                        wave-uniform scalar loads (s_load_dwordx4).
//   blocks [0, HBLK):    harmonic counts for batch LASTB (8 i's per block),
//                        last block to finish performs the selection.
// ---------------------------------------------------------------------------
__global__ __launch_bounds__(256, 1) void fused(
    const float* __restrict__ freqs, const float* __restrict__ mags,
    const float* __restrict__ W1, const float* __restrict__ b1,
    const float* __restrict__ W2, const float* __restrict__ b2,
    const float* __restrict__ W3, const float* __restrict__ b3,
    float* __restrict__ out, unsigned int* __restrict__ ticket,
    int* __restrict__ cnt)
{
    const int t = threadIdx.x;

    if (blockIdx.x >= HBLK) {
        // =================== MLP path ===================
        const int p = (blockIdx.x - HBLK) * 256 + t;
        const float f = freqs[p];
        const float m = mags[p];

        // layer 1: h1 = relu(f*W1[0][k] + m*W1[1][k] + b1[k]) -> 128 VGPRs
        float h1[HID];
#pragma unroll
        for (int k = 0; k < HID; ++k)
            h1[k] = fmaxf(fmaf(f, W1[k], fmaf(m, W1[HID + k], b1[k])), 0.0f);

        float o8[8];
#pragma unroll
        for (int o = 0; o < 8; ++o) o8[o] = b3[o];

        const float4* __restrict__ w2v = reinterpret_cast<const float4*>(W2);
        const float4* __restrict__ b2v = reinterpret_cast<const float4*>(b2);
        const float4* __restrict__ w3v = reinterpret_cast<const float4*>(W3);

        // layers 2+3: n-tile of 16 columns; per k one 64B line of W2
        for (int n0 = 0; n0 < HID; n0 += 16) {
            const int nq = n0 >> 2;
            float4 a0 = b2v[nq];
            float4 a1 = b2v[nq + 1];
            float4 a2 = b2v[nq + 2];
            float4 a3 = b2v[nq + 3];
#pragma unroll
            for (int k = 0; k < HID; ++k) {
                const float hv = h1[k];
                const float4 q0 = w2v[k * 32 + nq];
                const float4 q1 = w2v[k * 32 + nq + 1];
                const float4 q2 = w2v[k * 32 + nq + 2];
                const float4 q3 = w2v[k * 32 + nq + 3];
                a0.x = fmaf(hv, q0.x, a0.x); a0.y = fmaf(hv, q0.y, a0.y);
                a0.z = fmaf(hv, q0.z, a0.z); a0.w = fmaf(hv, q0.w, a0.w);
                a1.x = fmaf(hv, q1.x, a1.x); a1.y = fmaf(hv, q1.y, a1.y);
                a1.z = fmaf(hv, q1.z, a1.z); a1.w = fmaf(hv, q1.w, a1.w);
                a2.x = fmaf(hv, q2.x, a2.x); a2.y = fmaf(hv, q2.y, a2.y);
                a2.z = fmaf(hv, q2.z, a2.z); a2.w = fmaf(hv, q2.w, a2.w);
                a3.x = fmaf(hv, q3.x, a3.x); a3.y = fmaf(hv, q3.y, a3.y);
                a3.z = fmaf(hv, q3.z, a3.z); a3.w = fmaf(hv, q3.w, a3.w);
            }
            float hv16[16] = {
                fmaxf(a0.x, 0.0f), fmaxf(a0.y, 0.0f), fmaxf(a0.z, 0.0f), fmaxf(a0.w, 0.0f),
                fmaxf(a1.x, 0.0f), fmaxf(a1.y, 0.0f), fmaxf(a1.z, 0.0f), fmaxf(a1.w, 0.0f),
                fmaxf(a2.x, 0.0f), fmaxf(a2.y, 0.0f), fmaxf(a2.z, 0.0f), fmaxf(a2.w, 0.0f),
                fmaxf(a3.x, 0.0f), fmaxf(a3.y, 0.0f), fmaxf(a3.z, 0.0f), fmaxf(a3.w, 0.0f)};
#pragma unroll
            for (int j = 0; j < 16; ++j) {
                const float hv = hv16[j];
                const float4 wa = w3v[(n0 + j) * 2];
                const float4 wb = w3v[(n0 + j) * 2 + 1];
                o8[0] = fmaf(hv, wa.x, o8[0]); o8[1] = fmaf(hv, wa.y, o8[1]);
                o8[2] = fmaf(hv, wa.z, o8[2]); o8[3] = fmaf(hv, wa.w, o8[3]);
                o8[4] = fmaf(hv, wb.x, o8[4]); o8[5] = fmaf(hv, wb.y, o8[5]);
                o8[6] = fmaf(hv, wb.z, o8[6]); o8[7] = fmaf(hv, wb.w, o8[7]);
            }
        }
        float4* op = reinterpret_cast<float4*>(out + (size_t)p * 8);
        op[0] = make_float4(o8[0], o8[1], o8[2], o8[3]);
        op[1] = make_float4(o8[4], o8[5], o8[6], o8[7]);
        return;
    }

    // =================== harmonic path ===================
    __shared__ float sf[PNUM];
    __shared__ float sm[PNUM];
    __shared__ unsigned long long sc[256];
    __shared__ unsigned long long sfb[256];
    __shared__ int sLast;

    const float* fb = freqs + (size_t)LASTB * PNUM;
    const float* mb = mags  + (size_t)LASTB * PNUM;
#pragma unroll
    for (int r = 0; r < 4; ++r) {
        sf[t + 256 * r] = fb[t + 256 * r];
        sm[t + 256 * r] = mb[t + 256 * r];
    }
    __syncthreads();

    const int il = t >> 5;               // 0..7: which i in this block
    const int jc = t & 31;               // lane within the 32-wide j scan
    const int i  = blockIdx.x * 8 + il;
    const float fi = sf[i];
    float fo[7];
#pragma unroll
    for (int o = 0; o < 7; ++o) fo[o] = __fmul_rn(fi, (float)(o + 2));

    int c = 0;
#pragma unroll 4
    for (int jj = 0; jj < 32; ++jj) {
        const int j = jj * 32 + jc;      // consecutive per lane: conflict-free
        const float fj = sf[j];
        bool match = false;
#pragma unroll
        for (int o = 0; o < 7; ++o)
            match = match || (fabsf(__fsub_rn(fj, fo[o])) < 2.0f);
        if (match && (sm[j] > 0.0f) && (j != i)) ++c;
    }
#pragma unroll
    for (int off = 16; off > 0; off >>= 1) c += __shfl_down(c, off, 32);
    if (jc == 0)
        __hip_atomic_store(&cnt[i], c, __ATOMIC_RELAXED, __HIP_MEMORY_SCOPE_AGENT);
    __syncthreads();

    if (t == 0) {
        __threadfence();   // agent-scope release of this block's cnt stores
        const unsigned int old = __hip_atomic_fetch_add(
            ticket, 1u, __ATOMIC_ACQ_REL, __HIP_MEMORY_SCOPE_AGENT);
        sLast = (old == HBLK - 1) ? 1 : 0;
    }
    __syncthreads();
    if (!sLast) return;
    __threadfence();       // acquire side: make all cnt stores visible

    // -------- selection (this block only) --------
    unsigned long long ck = 0ull, fk = 0ull;
#pragma unroll
    for (int r = 0; r < 4; ++r) {
        const int i2 = t + 256 * r;
        const float mi = sm[i2];
        const int h = __hip_atomic_load(&cnt[i2], __ATOMIC_RELAXED,
                                        __HIP_MEMORY_SCOPE_AGENT);
        const unsigned mbits = __float_as_uint(mi);
        if (mi > 0.0f && h > 0) {
            // mag>0 => positive float bits are order-preserving (31 bits)
            const unsigned long long k =
                ((unsigned long long)h << 42) |
                ((unsigned long long)mbits << 10) |
                (unsigned long long)(1023 - i2);
            ck = umax64(ck, k);
        }
        const unsigned mo = (mbits & 0x80000000u) ? ~mbits : (mbits | 0x80000000u);
        const unsigned long long k2 =
            ((unsigned long long)mo << 10) | (unsigned long long)(1023 - i2);
        fk = umax64(fk, k2);
    }
    sc[t] = ck;
    sfb[t] = fk;
    __syncthreads();
    for (int s = 128; s > 0; s >>= 1) {
        if (t < s) {
            sc[t]  = umax64(sc[t],  sc[t + s]);
            sfb[t] = umax64(sfb[t], sfb[t + s]);
        }
        __syncthreads();
    }
    if (t == 0) {
        const unsigned long long k = sc[0] ? sc[0] : sfb[0];
        const int idx = 1023 - (int)(k & 1023ull);
        out[(size_t)BP * 8] = sf[idx];
    }
}

// ---------------------------------------------------------------------------
extern "C" void kernel_launch(void* const* d_in, const int* in_sizes, int n_in,
                              void* d_out, int out_size, void* d_ws, size_t ws_size,
                              hipStream_t stream) {
    const float* freqs = (const float*)d_in[0];
    const float* mags  = (const float*)d_in[1];
    const float* W1    = (const float*)d_in[2];
    const float* b1    = (const float*)d_in[3];
    const float* W2    = (const float*)d_in[4];
    const float* b2    = (const float*)d_in[5];
    const float* W3    = (const float*)d_in[6];
    const float* b3    = (const float*)d_in[7];
    float* out = (float*)d_out;

    unsigned int* ticket = (unsigned int*)d_ws;            // 1 counter
    int* cnt = (int*)((char*)d_ws + 256);                  // 1024 ints

    hipMemsetAsync(d_ws, 0, 4, stream);                    // zero the ticket
    fused<<<NBLK, 256, 0, stream>>>(freqs, mags, W1, b1, W2, b2, W3, b3,
                                    out, ticket, cnt);
}

// Round 3
// 160.075 us; speedup vs baseline: 1.0422x; 1.0422x over previous
//
#include <hip/hip_runtime.h>

#define HID   128
#define PNUM  1024
#define NB    64
#define LASTB 63
#define BP    (NB * PNUM)   // 65536 points
#define HBLK  128           // blocks that also run the harmonic prologue
#define NBLK  256           // total blocks == CU count (1 block/CU)

__device__ __forceinline__ unsigned long long umax64(unsigned long long a,
                                                     unsigned long long b) {
    return a > b ? a : b;
}

// ---------------------------------------------------------------------------
// One kernel, 256 blocks x 256 threads (1 block/CU).
// Every block: MLP for points [blockIdx*256, +256), 1 point/thread.
//   Layer-1 is RECOMPUTED inside each 16-column n-tile so no h1[128] array
//   exists -> no spills (R1 post-mortem: VGPR=84 forced h1 to scratch).
//   W1/W2/W3/b* are wave-uniform -> s_load into SGPRs; inner loop is pure
//   VALU (v_fmac_f32 acc, sW2, vH).
// Blocks [0, HBLK) first run the harmonic-count prologue for batch LASTB
//   (8 i's per block); the last to finish does the selection. ~1-2 us.
// ---------------------------------------------------------------------------
__global__ __launch_bounds__(256, 1) void fused(
    const float* __restrict__ freqs, const float* __restrict__ mags,
    const float* __restrict__ W1, const float* __restrict__ b1,
    const float* __restrict__ W2, const float* __restrict__ b2,
    const float* __restrict__ W3, const float* __restrict__ b3,
    float* __restrict__ out, unsigned int* __restrict__ ticket,
    int* __restrict__ cnt)
{
    __shared__ float sf[PNUM];
    __shared__ float sm[PNUM];
    __shared__ unsigned long long sc[256];
    __shared__ unsigned long long sfb[256];
    __shared__ int sLast;

    const int t = threadIdx.x;
    const int b = blockIdx.x;

    if (b < HBLK) {
        // =================== harmonic prologue ===================
        const float* fb = freqs + (size_t)LASTB * PNUM;
        const float* mb = mags  + (size_t)LASTB * PNUM;
#pragma unroll
        for (int r = 0; r < 4; ++r) {
            sf[t + 256 * r] = fb[t + 256 * r];
            sm[t + 256 * r] = mb[t + 256 * r];
        }
        __syncthreads();

        const int il = t >> 5;               // 0..7: which i in this block
        const int jc = t & 31;               // lane within the 32-wide j scan
        const int i  = b * 8 + il;
        const float fi = sf[i];
        float fo[7];
#pragma unroll
        for (int o = 0; o < 7; ++o) fo[o] = __fmul_rn(fi, (float)(o + 2));

        int c = 0;
#pragma unroll 4
        for (int jj = 0; jj < 32; ++jj) {
            const int j = jj * 32 + jc;      // consecutive per lane: conflict-free
            const float fj = sf[j];
            bool match = false;
#pragma unroll
            for (int o = 0; o < 7; ++o)
                match = match || (fabsf(__fsub_rn(fj, fo[o])) < 2.0f);
            if (match && (sm[j] > 0.0f) && (j != i)) ++c;
        }
#pragma unroll
        for (int off = 16; off > 0; off >>= 1) c += __shfl_down(c, off, 32);
        if (jc == 0)
            __hip_atomic_store(&cnt[i], c, __ATOMIC_RELAXED,
                               __HIP_MEMORY_SCOPE_AGENT);
        __syncthreads();

        if (t == 0) {
            __threadfence();   // release this block's cnt stores (agent scope)
            const unsigned int old = __hip_atomic_fetch_add(
                ticket, 1u, __ATOMIC_ACQ_REL, __HIP_MEMORY_SCOPE_AGENT);
            sLast = (old == HBLK - 1) ? 1 : 0;
        }
        __syncthreads();

        if (sLast) {
            __threadfence();   // acquire: all cnt stores visible
            unsigned long long ck = 0ull, fk = 0ull;
#pragma unroll
            for (int r = 0; r < 4; ++r) {
                const int i2 = t + 256 * r;
                const float mi = sm[i2];
                const int h = __hip_atomic_load(&cnt[i2], __ATOMIC_RELAXED,
                                                __HIP_MEMORY_SCOPE_AGENT);
                const unsigned mbits = __float_as_uint(mi);
                if (mi > 0.0f && h > 0) {
                    // mag>0 => positive float bits order-preserving (31 bits)
                    const unsigned long long k =
                        ((unsigned long long)h << 42) |
                        ((unsigned long long)mbits << 10) |
                        (unsigned long long)(1023 - i2);
                    ck = umax64(ck, k);
                }
                const unsigned mo =
                    (mbits & 0x80000000u) ? ~mbits : (mbits | 0x80000000u);
                const unsigned long long k2 =
                    ((unsigned long long)mo << 10) |
                    (unsigned long long)(1023 - i2);
                fk = umax64(fk, k2);
            }
            sc[t] = ck;
            sfb[t] = fk;
            __syncthreads();
            for (int s = 128; s > 0; s >>= 1) {
                if (t < s) {
                    sc[t]  = umax64(sc[t],  sc[t + s]);
                    sfb[t] = umax64(sfb[t], sfb[t + s]);
                }
                __syncthreads();
            }
            if (t == 0) {
                const unsigned long long k = sc[0] ? sc[0] : sfb[0];
                const int idx = 1023 - (int)(k & 1023ull);
                out[(size_t)BP * 8] = sf[idx];
            }
        }
    }

    // =================== MLP (all blocks) ===================
    const int p = b * 256 + t;
    const float f = freqs[p];
    const float m = mags[p];

    float o8[8];
#pragma unroll
    for (int o = 0; o < 8; ++o) o8[o] = b3[o];

    const float4* __restrict__ w2v = reinterpret_cast<const float4*>(W2);
    const float4* __restrict__ b2v = reinterpret_cast<const float4*>(b2);
    const float4* __restrict__ w3v = reinterpret_cast<const float4*>(W3);

    for (int n0 = 0; n0 < HID; n0 += 16) {     // 8 n-tiles of 16 columns
        const int nq = n0 >> 2;
        float4 a0 = b2v[nq];
        float4 a1 = b2v[nq + 1];
        float4 a2 = b2v[nq + 2];
        float4 a3 = b2v[nq + 3];
#pragma unroll
        for (int k = 0; k < HID; ++k) {
            // recompute layer-1 activation (no h1 array -> no spills)
            const float hv =
                fmaxf(fmaf(f, W1[k], fmaf(m, W1[HID + k], b1[k])), 0.0f);
            const float4 q0 = w2v[k * 32 + nq];
            const float4 q1 = w2v[k * 32 + nq + 1];
            const float4 q2 = w2v[k * 32 + nq + 2];
            const float4 q3 = w2v[k * 32 + nq + 3];
            a0.x = fmaf(hv, q0.x, a0.x); a0.y = fmaf(hv, q0.y, a0.y);
            a0.z = fmaf(hv, q0.z, a0.z); a0.w = fmaf(hv, q0.w, a0.w);
            a1.x = fmaf(hv, q1.x, a1.x); a1.y = fmaf(hv, q1.y, a1.y);
            a1.z = fmaf(hv, q1.z, a1.z); a1.w = fmaf(hv, q1.w, a1.w);
            a2.x = fmaf(hv, q2.x, a2.x); a2.y = fmaf(hv, q2.y, a2.y);
            a2.z = fmaf(hv, q2.z, a2.z); a2.w = fmaf(hv, q2.w, a2.w);
            a3.x = fmaf(hv, q3.x, a3.x); a3.y = fmaf(hv, q3.y, a3.y);
            a3.z = fmaf(hv, q3.z, a3.z); a3.w = fmaf(hv, q3.w, a3.w);
        }
        const float hv16[16] = {
            fmaxf(a0.x, 0.0f), fmaxf(a0.y, 0.0f), fmaxf(a0.z, 0.0f), fmaxf(a0.w, 0.0f),
            fmaxf(a1.x, 0.0f), fmaxf(a1.y, 0.0f), fmaxf(a1.z, 0.0f), fmaxf(a1.w, 0.0f),
            fmaxf(a2.x, 0.0f), fmaxf(a2.y, 0.0f), fmaxf(a2.z, 0.0f), fmaxf(a2.w, 0.0f),
            fmaxf(a3.x, 0.0f), fmaxf(a3.y, 0.0f), fmaxf(a3.z, 0.0f), fmaxf(a3.w, 0.0f)};
#pragma unroll
        for (int j = 0; j < 16; ++j) {
            const float hv = hv16[j];
            const float4 wa = w3v[(n0 + j) * 2];
            const float4 wb = w3v[(n0 + j) * 2 + 1];
            o8[0] = fmaf(hv, wa.x, o8[0]); o8[1] = fmaf(hv, wa.y, o8[1]);
            o8[2] = fmaf(hv, wa.z, o8[2]); o8[3] = fmaf(hv, wa.w, o8[3]);
            o8[4] = fmaf(hv, wb.x, o8[4]); o8[5] = fmaf(hv, wb.y, o8[5]);
            o8[6] = fmaf(hv, wb.z, o8[6]); o8[7] = fmaf(hv, wb.w, o8[7]);
        }
    }
    float4* op = reinterpret_cast<float4*>(out + (size_t)p * 8);
    op[0] = make_float4(o8[0], o8[1], o8[2], o8[3]);
    op[1] = make_float4(o8[4], o8[5], o8[6], o8[7]);
}

// ---------------------------------------------------------------------------
extern "C" void kernel_launch(void* const* d_in, const int* in_sizes, int n_in,
                              void* d_out, int out_size, void* d_ws, size_t ws_size,
                              hipStream_t stream) {
    const float* freqs = (const float*)d_in[0];
    const float* mags  = (const float*)d_in[1];
    const float* W1    = (const float*)d_in[2];
    const float* b1    = (const float*)d_in[3];
    const float* W2    = (const float*)d_in[4];
    const float* b2    = (const float*)d_in[5];
    const float* W3    = (const float*)d_in[6];
    const float* b3    = (const float*)d_in[7];
    float* out = (float*)d_out;

    unsigned int* ticket = (unsigned int*)d_ws;            // 1 counter
    int* cnt = (int*)((char*)d_ws + 256);                  // 1024 ints

    hipMemsetAsync(d_ws, 0, 4, stream);                    // zero the ticket
    fused<<<NBLK, 256, 0, stream>>>(freqs, mags, W1, b1, W2, b2, W3, b3,
                                    out, ticket, cnt);
}

// Round 4
// 96.667 us; speedup vs baseline: 1.7258x; 1.6559x over previous
//
#include <hip/hip_runtime.h>

#define HID   128
#define PNUM  1024
#define LASTB 63
#define BP    (64 * PNUM)   // 65536 points
#define HBLK  128           // blocks that run the harmonic prologue
#define NBLK  512           // 128 points per block, 2 blocks/CU
#define PPB   128           // points per block
#define WS    136           // LDS row stride in bf16 units (16B-aligned pad)

typedef __attribute__((ext_vector_type(8))) short short8;   // 8 bf16 = 4 VGPRs
typedef __attribute__((ext_vector_type(4))) float f32x4;    // MFMA C/D

__device__ __forceinline__ unsigned short f2bf(float x) {
    // RNE float->bf16 (matches __float2bfloat16 for finite values)
    unsigned u = __float_as_uint(x);
    return (unsigned short)((u + 0x7FFFu + ((u >> 16) & 1u)) >> 16);
}

__device__ __forceinline__ unsigned long long umax64(unsigned long long a,
                                                     unsigned long long b) {
    return a > b ? a : b;
}

// ---------------------------------------------------------------------------
// One kernel, 512 blocks x 256 threads (2 blocks/CU).
// MLP: per wave 32 points (2 M-tiles), mfma_f32_16x16x32_bf16.
//   A-frag (h1) computed in regs: A[m=lane&15][k=quad*8+j]  (m120 layout)
//   B-frag (W2) from LDS W2^T bf16: B[k=quad*8+j][n=lane&15]
//   C/D: row=quad*4+reg (point), col=lane&15 (m89 layout)
//   Layer-3 via per-wave LDS round-trip (C-layout -> A-layout), W3 zero-padded
//   to 16 cols.
// Blocks [0,HBLK): harmonic-count prologue for batch LASTB first; last ticket
//   does the selection.
// ---------------------------------------------------------------------------
__global__ __launch_bounds__(256) void fused(
    const float* __restrict__ freqs, const float* __restrict__ mags,
    const float* __restrict__ W1, const float* __restrict__ b1,
    const float* __restrict__ W2, const float* __restrict__ b2,
    const float* __restrict__ W3, const float* __restrict__ b3,
    float* __restrict__ out, unsigned int* __restrict__ ticket,
    int* __restrict__ cnt)
{
    __shared__ unsigned short sW2T[HID * WS];     // 34816 B: W2^T bf16
    __shared__ unsigned short sW3T[16 * WS];      //  4352 B: W3^T bf16, rows 8..15 = 0
    __shared__ unsigned short sH2[4][16 * WS];    // 17408 B: per-wave h2 tile
    __shared__ float sf[PNUM], sm[PNUM];          //  8192 B: harm freqs/mags
    __shared__ unsigned long long sc[256], sfb[256]; // 4096 B: selection keys
    __shared__ int sLast;

    const int t = threadIdx.x;
    const int b = blockIdx.x;

    if (b < HBLK) {
        // =================== harmonic prologue ===================
        const float* fb = freqs + (size_t)LASTB * PNUM;
        const float* mb = mags  + (size_t)LASTB * PNUM;
#pragma unroll
        for (int r = 0; r < 4; ++r) {
            sf[t + 256 * r] = fb[t + 256 * r];
            sm[t + 256 * r] = mb[t + 256 * r];
        }
        __syncthreads();

        const int il = t >> 5;
        const int jc = t & 31;
        const int i  = b * 8 + il;
        const float fi = sf[i];
        float fo[7];
#pragma unroll
        for (int o = 0; o < 7; ++o) fo[o] = __fmul_rn(fi, (float)(o + 2));

        int c = 0;
#pragma unroll 4
        for (int jj = 0; jj < 32; ++jj) {
            const int j = jj * 32 + jc;
            const float fj = sf[j];
            bool match = false;
#pragma unroll
            for (int o = 0; o < 7; ++o)
                match = match || (fabsf(__fsub_rn(fj, fo[o])) < 2.0f);
            if (match && (sm[j] > 0.0f) && (j != i)) ++c;
        }
#pragma unroll
        for (int off = 16; off > 0; off >>= 1) c += __shfl_down(c, off, 32);
        if (jc == 0)
            __hip_atomic_store(&cnt[i], c, __ATOMIC_RELAXED,
                               __HIP_MEMORY_SCOPE_AGENT);
        __syncthreads();

        if (t == 0) {
            __threadfence();
            const unsigned int old = __hip_atomic_fetch_add(
                ticket, 1u, __ATOMIC_ACQ_REL, __HIP_MEMORY_SCOPE_AGENT);
            sLast = (old == HBLK - 1) ? 1 : 0;
        }
        __syncthreads();

        if (sLast) {
            __threadfence();
            unsigned long long ck = 0ull, fk = 0ull;
#pragma unroll
            for (int r = 0; r < 4; ++r) {
                const int i2 = t + 256 * r;
                const float mi = sm[i2];
                const int h = __hip_atomic_load(&cnt[i2], __ATOMIC_RELAXED,
                                                __HIP_MEMORY_SCOPE_AGENT);
                const unsigned mbits = __float_as_uint(mi);
                if (mi > 0.0f && h > 0) {
                    const unsigned long long k =
                        ((unsigned long long)h << 42) |
                        ((unsigned long long)mbits << 10) |
                        (unsigned long long)(1023 - i2);
                    ck = umax64(ck, k);
                }
                const unsigned mo =
                    (mbits & 0x80000000u) ? ~mbits : (mbits | 0x80000000u);
                const unsigned long long k2 =
                    ((unsigned long long)mo << 10) |
                    (unsigned long long)(1023 - i2);
                fk = umax64(fk, k2);
            }
            sc[t] = ck;
            sfb[t] = fk;
            __syncthreads();
            for (int s = 128; s > 0; s >>= 1) {
                if (t < s) {
                    sc[t]  = umax64(sc[t],  sc[t + s]);
                    sfb[t] = umax64(sfb[t], sfb[t + s]);
                }
                __syncthreads();
            }
            if (t == 0) {
                const unsigned long long k = sc[0] ? sc[0] : sfb[0];
                const int idx = 1023 - (int)(k & 1023ull);
                out[(size_t)BP * 8] = sf[idx];
            }
        }
    }

    // =================== stage W2^T (fp32 -> bf16) ===================
    {
        const float4* __restrict__ w2v = reinterpret_cast<const float4*>(W2);
#pragma unroll
        for (int rep = 0; rep < 16; ++rep) {
            const int e  = rep * 256 + t;        // [0, 4096)
            const int k  = e >> 5;               // row of W2
            const int n0 = (e & 31) * 4;         // col group
            const float4 v = w2v[e];
            sW2T[(n0 + 0) * WS + k] = f2bf(v.x);
            sW2T[(n0 + 1) * WS + k] = f2bf(v.y);
            sW2T[(n0 + 2) * WS + k] = f2bf(v.z);
            sW2T[(n0 + 3) * WS + k] = f2bf(v.w);
        }
    }
    // =================== stage W3^T, rows 8..15 zeroed ===================
    {
#pragma unroll
        for (int rep = 0; rep < 5; ++rep) {
            const int idx = rep * 256 + t;
            if (idx < 8 * WS) sW3T[8 * WS + idx] = 0;
        }
#pragma unroll
        for (int rep = 0; rep < 4; ++rep) {
            const int e = rep * 256 + t;         // [0, 1024)
            const int k = e >> 3, o = e & 7;     // W3[k][o]
            sW3T[o * WS + k] = f2bf(W3[e]);
        }
    }

    // =================== per-lane MFMA setup ===================
    const int w    = t >> 6;
    const int lane = t & 63;
    const int cc   = lane & 15;   // A row / B col / C col within tile
    const int q    = lane >> 4;   // quad
    const int pb   = b * PPB + w * 32;

    // A-frags: h1 for 2 M-tiles x 4 k-chunks, A[m=cc][k=kc*32+q*8+j]
    short8 af[2][4];
#pragma unroll
    for (int mt = 0; mt < 2; ++mt) {
        const int p = pb + mt * 16 + cc;
        const float fv = freqs[p];
        const float mv = mags[p];
#pragma unroll
        for (int kc = 0; kc < 4; ++kc) {
            const int k0 = kc * 32 + q * 8;
            const float4 wa0 = *(const float4*)&W1[k0];
            const float4 wa1 = *(const float4*)&W1[k0 + 4];
            const float4 wb0 = *(const float4*)&W1[HID + k0];
            const float4 wb1 = *(const float4*)&W1[HID + k0 + 4];
            const float4 bb0 = *(const float4*)&b1[k0];
            const float4 bb1 = *(const float4*)&b1[k0 + 4];
            float hv[8];
            hv[0] = fmaxf(fmaf(fv, wa0.x, fmaf(mv, wb0.x, bb0.x)), 0.0f);
            hv[1] = fmaxf(fmaf(fv, wa0.y, fmaf(mv, wb0.y, bb0.y)), 0.0f);
            hv[2] = fmaxf(fmaf(fv, wa0.z, fmaf(mv, wb0.z, bb0.z)), 0.0f);
            hv[3] = fmaxf(fmaf(fv, wa0.w, fmaf(mv, wb0.w, bb0.w)), 0.0f);
            hv[4] = fmaxf(fmaf(fv, wa1.x, fmaf(mv, wb1.x, bb1.x)), 0.0f);
            hv[5] = fmaxf(fmaf(fv, wa1.y, fmaf(mv, wb1.y, bb1.y)), 0.0f);
            hv[6] = fmaxf(fmaf(fv, wa1.z, fmaf(mv, wb1.z, bb1.z)), 0.0f);
            hv[7] = fmaxf(fmaf(fv, wa1.w, fmaf(mv, wb1.w, bb1.w)), 0.0f);
#pragma unroll
            for (int j = 0; j < 8; ++j) af[mt][kc][j] = (short)f2bf(hv[j]);
        }
    }

    float b2v[8];
#pragma unroll
    for (int nt = 0; nt < 8; ++nt) b2v[nt] = b2[nt * 16 + cc];
    const float b3v = (cc < 8) ? b3[cc] : 0.0f;

    __syncthreads();

    // W3 B-frags: B[k=kc*32+q*8+j][n=cc]
    short8 bw3[4];
#pragma unroll
    for (int kc = 0; kc < 4; ++kc)
        bw3[kc] = *(const short8*)&sW3T[cc * WS + kc * 32 + q * 8];

    // =================== layer 2: 64 MFMAs ===================
    f32x4 acc[2][8];
#pragma unroll
    for (int mt = 0; mt < 2; ++mt)
#pragma unroll
        for (int nt = 0; nt < 8; ++nt) {
            f32x4 z = {0.0f, 0.0f, 0.0f, 0.0f};
            acc[mt][nt] = z;
        }

#pragma unroll
    for (int nt = 0; nt < 8; ++nt)
#pragma unroll
        for (int kc = 0; kc < 4; ++kc) {
            const short8 bf =
                *(const short8*)&sW2T[(nt * 16 + cc) * WS + kc * 32 + q * 8];
            acc[0][nt] = __builtin_amdgcn_mfma_f32_16x16x32_bf16(
                af[0][kc], bf, acc[0][nt], 0, 0, 0);
            acc[1][nt] = __builtin_amdgcn_mfma_f32_16x16x32_bf16(
                af[1][kc], bf, acc[1][nt], 0, 0, 0);
        }

    // =================== layer 3 + store, per M-tile ===================
    unsigned short* __restrict__ myH2 = sH2[w];
#pragma unroll
    for (int mt = 0; mt < 2; ++mt) {
        // C-layout -> LDS: row = q*4+r (point), col = nt*16+cc (h2 col)
#pragma unroll
        for (int nt = 0; nt < 8; ++nt) {
            const f32x4 v = acc[mt][nt];
#pragma unroll
            for (int r = 0; r < 4; ++r)
                myH2[(q * 4 + r) * WS + nt * 16 + cc] =
                    f2bf(fmaxf(v[r] + b2v[nt], 0.0f));
        }
        // read back in A-layout (wave-internal; compiler inserts lgkmcnt)
        f32x4 oa = {0.0f, 0.0f, 0.0f, 0.0f};
#pragma unroll
        for (int kc = 0; kc < 4; ++kc) {
            const short8 a3 = *(const short8*)&myH2[cc * WS + kc * 32 + q * 8];
            oa = __builtin_amdgcn_mfma_f32_16x16x32_bf16(a3, bw3[kc], oa, 0, 0, 0);
        }
        if (cc < 8) {
            const int pg = pb + mt * 16 + q * 4;
#pragma unroll
            for (int r = 0; r < 4; ++r)
                out[(size_t)(pg + r) * 8 + cc] = oa[r] + b3v;
        }
    }
}

// ---------------------------------------------------------------------------
extern "C" void kernel_launch(void* const* d_in, const int* in_sizes, int n_in,
                              void* d_out, int out_size, void* d_ws, size_t ws_size,
                              hipStream_t stream) {
    const float* freqs = (const float*)d_in[0];
    const float* mags  = (const float*)d_in[1];
    const float* W1    = (const float*)d_in[2];
    const float* b1    = (const float*)d_in[3];
    const float* W2    = (const float*)d_in[4];
    const float* b2    = (const float*)d_in[5];
    const float* W3    = (const float*)d_in[6];
    const float* b3    = (const float*)d_in[7];
    float* out = (float*)d_out;

    unsigned int* ticket = (unsigned int*)d_ws;
    int* cnt = (int*)((char*)d_ws + 256);

    hipMemsetAsync(d_ws, 0, 4, stream);
    fused<<<NBLK, 256, 0, stream>>>(freqs, mags, W1, b1, W2, b2, W3, b3,
                                    out, ticket, cnt);
}